// Round 1
// baseline (637.299 us; speedup 1.0000x reference)
//
#include <hip/hip_runtime.h>

#define EDIM 2048
#define BM 128
#define BN 128
#define BK 32
#define LP 40   // padded LDS pitch in bf16 elements (40*2=80B, 16B-aligned, conflict-free)

typedef unsigned short u16;
typedef __attribute__((ext_vector_type(8))) __bf16 bf16x8;
typedef __attribute__((ext_vector_type(4))) float f32x4;

__device__ __forceinline__ u16 f2bf(float f) {
    __bf16 h = (__bf16)f;
    return __builtin_bit_cast(u16, h);
}
__device__ __forceinline__ float bf2f(u16 u) {
    __bf16 h = __builtin_bit_cast(__bf16, u);
    return (float)h;
}

// ---------------------------------------------------------------------------
// 32x32 LDS-tiled fp32 transpose: out[j][i] = in[i][j]   (n x n, n % 32 == 0)
// ---------------------------------------------------------------------------
__global__ void transpose_f32(const float* __restrict__ in, float* __restrict__ out, int n) {
    __shared__ float tile[32][33];
    const int bx = blockIdx.x * 32, by = blockIdx.y * 32;
    const int tx = threadIdx.x & 31, ty = threadIdx.x >> 5;  // 32 x 8 threads
    #pragma unroll
    for (int r = ty; r < 32; r += 8)
        tile[r][tx] = in[(size_t)(by + r) * n + bx + tx];
    __syncthreads();
    #pragma unroll
    for (int r = ty; r < 32; r += 8)
        out[(size_t)(bx + r) * n + by + tx] = tile[tx][r];
}

// ---------------------------------------------------------------------------
// bp[n] = bc[n] + sum_j bv[j] * Wc[j][n]   (bp must be zeroed first)
// grid (EDIM/256, EDIM/128), 256 threads
// ---------------------------------------------------------------------------
__global__ void bias_kernel(const float* __restrict__ bv, const float* __restrict__ Wc,
                            const float* __restrict__ bc, float* __restrict__ bp) {
    const int n = blockIdx.x * 256 + threadIdx.x;
    const int j0 = blockIdx.y * 128;
    float s = (blockIdx.y == 0) ? bc[n] : 0.0f;
    for (int j = 0; j < 128; ++j)
        s += bv[j0 + j] * Wc[(size_t)(j0 + j) * EDIM + n];
    atomicAdd(&bp[n], s);
}

// ---------------------------------------------------------------------------
// Split-precision bf16 MFMA GEMM:  C[M][N] = A[M][K] * B[K][N]
//   A: fp32 [M][K], converted to hi/lo bf16 on the fly.
//   B: either pre-split bf16 hi/lo stored transposed [N][K] (BSPLIT=1),
//      or fp32 stored transposed [N][K] (BSPLIT=0), converted on the fly.
//   3-term accumulate: A_hi*B_hi + A_hi*B_lo + A_lo*B_hi  (~2^-17 rel err).
//   EPIL=0: Cout[m][n] = acc + bias[n]  (fp32)
//   EPIL=1: write bf16 hi/lo split of acc to Ohi/Olo at [m][n] (row-major)
// 256 threads = 4 waves (2x2), each wave 64x64 out = 4x4 frags of 16x16.
// ---------------------------------------------------------------------------
template<int EPIL, int BSPLIT>
__global__ __launch_bounds__(256)
void gemm_split(const float* __restrict__ Af,
                const u16* __restrict__ Bhi, const u16* __restrict__ Blo,
                const float* __restrict__ Btf,
                float* __restrict__ Cout, const float* __restrict__ bias,
                u16* __restrict__ Ohi, u16* __restrict__ Olo,
                int Kdim, int Ndim)
{
    __shared__ __align__(16) u16 lsAhi[BM * LP];
    __shared__ __align__(16) u16 lsAlo[BM * LP];
    __shared__ __align__(16) u16 lsBhi[BN * LP];
    __shared__ __align__(16) u16 lsBlo[BN * LP];

    const int tid  = threadIdx.x;
    const int lane = tid & 63;
    const int wave = tid >> 6;
    const int wm = wave >> 1, wn = wave & 1;
    const int lrow = lane & 15, kq = lane >> 4;
    const long m0 = (long)blockIdx.x * BM;
    const long n0 = (long)blockIdx.y * BN;

    f32x4 acc[4][4];
    #pragma unroll
    for (int i = 0; i < 4; ++i)
        #pragma unroll
        for (int j = 0; j < 4; ++j)
            acc[i][j] = (f32x4){0.f, 0.f, 0.f, 0.f};

    for (int kt = 0; kt < Kdim; kt += BK) {
        // ---- issue global loads into registers (overlaps previous compute) ----
        float4 av[4];
        #pragma unroll
        for (int i = 0; i < 4; ++i) {
            int ch = tid + i * 256;          // 1024 chunks of 4 floats = 128x32
            int row = ch >> 3, c4 = ch & 7;
            av[i] = *reinterpret_cast<const float4*>(Af + (m0 + row) * Kdim + kt + c4 * 4);
        }
        uint4 bh[2], bl[2];
        float4 bvv[4];
        if (BSPLIT) {
            #pragma unroll
            for (int i = 0; i < 2; ++i) {
                int ch = tid + i * 256;      // 512 chunks of 8 bf16 = 128x32
                int row = ch >> 2, c8 = ch & 3;
                bh[i] = *reinterpret_cast<const uint4*>(Bhi + (n0 + row) * Kdim + kt + c8 * 8);
                bl[i] = *reinterpret_cast<const uint4*>(Blo + (n0 + row) * Kdim + kt + c8 * 8);
            }
        } else {
            #pragma unroll
            for (int i = 0; i < 4; ++i) {
                int ch = tid + i * 256;
                int row = ch >> 3, c4 = ch & 7;
                bvv[i] = *reinterpret_cast<const float4*>(Btf + (n0 + row) * Kdim + kt + c4 * 4);
            }
        }

        __syncthreads();   // all waves done reading LDS from previous iteration

        // ---- A: convert fp32 -> hi/lo bf16, write to LDS ----
        #pragma unroll
        for (int i = 0; i < 4; ++i) {
            int ch = tid + i * 256;
            int row = ch >> 3, c4 = ch & 7;
            u16 h0 = f2bf(av[i].x), h1 = f2bf(av[i].y), h2 = f2bf(av[i].z), h3 = f2bf(av[i].w);
            u16 l0 = f2bf(av[i].x - bf2f(h0));
            u16 l1 = f2bf(av[i].y - bf2f(h1));
            u16 l2 = f2bf(av[i].z - bf2f(h2));
            u16 l3 = f2bf(av[i].w - bf2f(h3));
            ushort4 hv; hv.x = h0; hv.y = h1; hv.z = h2; hv.w = h3;
            ushort4 lv; lv.x = l0; lv.y = l1; lv.z = l2; lv.w = l3;
            *reinterpret_cast<ushort4*>(&lsAhi[row * LP + c4 * 4]) = hv;
            *reinterpret_cast<ushort4*>(&lsAlo[row * LP + c4 * 4]) = lv;
        }
        // ---- B ----
        if (BSPLIT) {
            #pragma unroll
            for (int i = 0; i < 2; ++i) {
                int ch = tid + i * 256;
                int row = ch >> 2, c8 = ch & 3;
                *reinterpret_cast<uint4*>(&lsBhi[row * LP + c8 * 8]) = bh[i];
                *reinterpret_cast<uint4*>(&lsBlo[row * LP + c8 * 8]) = bl[i];
            }
        } else {
            #pragma unroll
            for (int i = 0; i < 4; ++i) {
                int ch = tid + i * 256;
                int row = ch >> 3, c4 = ch & 7;
                u16 h0 = f2bf(bvv[i].x), h1 = f2bf(bvv[i].y), h2 = f2bf(bvv[i].z), h3 = f2bf(bvv[i].w);
                u16 l0 = f2bf(bvv[i].x - bf2f(h0));
                u16 l1 = f2bf(bvv[i].y - bf2f(h1));
                u16 l2 = f2bf(bvv[i].z - bf2f(h2));
                u16 l3 = f2bf(bvv[i].w - bf2f(h3));
                ushort4 hv; hv.x = h0; hv.y = h1; hv.z = h2; hv.w = h3;
                ushort4 lv; lv.x = l0; lv.y = l1; lv.z = l2; lv.w = l3;
                *reinterpret_cast<ushort4*>(&lsBhi[row * LP + c4 * 4]) = hv;
                *reinterpret_cast<ushort4*>(&lsBlo[row * LP + c4 * 4]) = lv;
            }
        }

        __syncthreads();   // LDS tile ready

        // ---- fragments + MFMA (3-term split) ----
        bf16x8 bfh[4], bfl[4];
        #pragma unroll
        for (int fn = 0; fn < 4; ++fn) {
            int r = wn * 64 + fn * 16 + lrow;
            bfh[fn] = *reinterpret_cast<const bf16x8*>(&lsBhi[r * LP + kq * 8]);
            bfl[fn] = *reinterpret_cast<const bf16x8*>(&lsBlo[r * LP + kq * 8]);
        }
        #pragma unroll
        for (int fm = 0; fm < 4; ++fm) {
            int r = wm * 64 + fm * 16 + lrow;
            bf16x8 ah = *reinterpret_cast<const bf16x8*>(&lsAhi[r * LP + kq * 8]);
            bf16x8 al = *reinterpret_cast<const bf16x8*>(&lsAlo[r * LP + kq * 8]);
            #pragma unroll
            for (int fn = 0; fn < 4; ++fn) {
                acc[fm][fn] = __builtin_amdgcn_mfma_f32_16x16x32_bf16(ah, bfh[fn], acc[fm][fn], 0, 0, 0);
                acc[fm][fn] = __builtin_amdgcn_mfma_f32_16x16x32_bf16(ah, bfl[fn], acc[fm][fn], 0, 0, 0);
                acc[fm][fn] = __builtin_amdgcn_mfma_f32_16x16x32_bf16(al, bfh[fn], acc[fm][fn], 0, 0, 0);
            }
        }
    }

    // ---- epilogue ----
    // C/D layout (verified, learn_hip m89): col = lane&15, row = (lane>>4)*4 + i
    #pragma unroll
    for (int fm = 0; fm < 4; ++fm) {
        long gmb = m0 + wm * 64 + fm * 16 + kq * 4;
        #pragma unroll
        for (int fn = 0; fn < 4; ++fn) {
            long gn = n0 + wn * 64 + fn * 16 + lrow;
            #pragma unroll
            for (int i = 0; i < 4; ++i) {
                long gm = gmb + i;
                float w = acc[fm][fn][i];
                if (EPIL == 0) {
                    Cout[gm * Ndim + gn] = w + bias[gn];
                } else {
                    u16 h = f2bf(w);
                    u16 l = f2bf(w - bf2f(h));
                    Ohi[gm * Ndim + gn] = h;
                    Olo[gm * Ndim + gn] = l;
                }
            }
        }
    }
}

// ---------------------------------------------------------------------------
// out = x @ (Wv @ Wc) + (bv @ Wc + bc)
//   (attention collapses: softmax rows sum to 1 -> y == v)
// ---------------------------------------------------------------------------
extern "C" void kernel_launch(void* const* d_in, const int* in_sizes, int n_in,
                              void* d_out, int out_size, void* d_ws, size_t ws_size,
                              hipStream_t stream) {
    const float* x  = (const float*)d_in[0];
    const float* Wv = (const float*)d_in[5];
    const float* bv = (const float*)d_in[6];
    const float* Wc = (const float*)d_in[7];
    const float* bc = (const float*)d_in[8];
    float* out = (float*)d_out;

    char* ws = (char*)d_ws;
    float* Wct    = (float*)ws;                        // 2048*2048*4  = 16 MiB
    u16*   Wpt_hi = (u16*)(ws + 16777216);             // 2048*2048*2  =  8 MiB
    u16*   Wpt_lo = (u16*)(ws + 25165824);             // 2048*2048*2  =  8 MiB
    float* bp     = (float*)(ws + 33554432);           // 2048*4

    const int M = 8192;  // B*S

    // 1) Wct = Wc^T (fp32)
    transpose_f32<<<dim3(EDIM / 32, EDIM / 32), 256, 0, stream>>>(Wc, Wct, EDIM);

    // 2) bp = bc + bv @ Wc
    hipMemsetAsync(bp, 0, EDIM * sizeof(float), stream);
    bias_kernel<<<dim3(EDIM / 256, EDIM / 128), 256, 0, stream>>>(bv, Wc, bc, bp);

    // 3) W'^T = Wc^T @ Wv^T  : A = Wct [n][j] fp32, Bt = Wv [kx][j] fp32
    //    output written as bf16 hi/lo split, row-major [n][kx]
    gemm_split<1, 0><<<dim3(EDIM / BM, EDIM / BN), 256, 0, stream>>>(
        Wct, nullptr, nullptr, Wv, nullptr, nullptr, Wpt_hi, Wpt_lo, EDIM, EDIM);

    // 4) out = x @ W' + bp : A = x [m][k] fp32, Bt = W'^T [n][k] bf16 hi/lo
    gemm_split<0, 1><<<dim3(M / BM, EDIM / BN), 256, 0, stream>>>(
        x, Wpt_hi, Wpt_lo, nullptr, out, bp, nullptr, nullptr, EDIM, EDIM);
}

// Round 3
// 620.024 us; speedup vs baseline: 1.0279x; 1.0279x over previous
//
#include <hip/hip_runtime.h>

#define ED 2048
#define MR 8192

typedef unsigned short u16;
typedef __attribute__((ext_vector_type(8))) __bf16 bf16x8;
typedef __attribute__((ext_vector_type(4))) float f32x4;

__device__ __forceinline__ u16 f2bf(float f){ __bf16 h=(__bf16)f; return __builtin_bit_cast(u16,h); }
__device__ __forceinline__ float bf2f(u16 u){ __bf16 h=__builtin_bit_cast(__bf16,u); return (float)h; }

// async global->LDS, 16B per lane; LDS dest is wave-uniform base + lane*16
#define LDSLOAD(gp, lp) __builtin_amdgcn_global_load_lds( \
    (const __attribute__((address_space(1))) unsigned int*)(gp), \
    (__attribute__((address_space(3))) unsigned int*)(lp), 16, 0, 0)

// ---------------------------------------------------------------------------
// split fp32 -> hi/lo bf16 (elementwise, float4 vectorized, grid-stride)
// ---------------------------------------------------------------------------
__global__ void split_kernel(const float* __restrict__ in, u16* __restrict__ hi,
                             u16* __restrict__ lo, int n4) {
    int i = blockIdx.x * 256 + threadIdx.x;
    const int stride = gridDim.x * 256;
    for (; i < n4; i += stride) {
        float4 v = reinterpret_cast<const float4*>(in)[i];
        ushort4 h, l;
        h.x = f2bf(v.x); l.x = f2bf(v.x - bf2f(h.x));
        h.y = f2bf(v.y); l.y = f2bf(v.y - bf2f(h.y));
        h.z = f2bf(v.z); l.z = f2bf(v.z - bf2f(h.z));
        h.w = f2bf(v.w); l.w = f2bf(v.w - bf2f(h.w));
        reinterpret_cast<ushort4*>(hi)[i] = h;
        reinterpret_cast<ushort4*>(lo)[i] = l;
    }
}

// ---------------------------------------------------------------------------
// 32x32 tiled transpose fp32 -> fp32 (minimal path)
// ---------------------------------------------------------------------------
__global__ void transpose_f32(const float* __restrict__ in, float* __restrict__ out, int n) {
    __shared__ float tile[32][33];
    const int bx = blockIdx.x * 32, by = blockIdx.y * 32;
    const int tx = threadIdx.x & 31, ty = threadIdx.x >> 5;
    #pragma unroll
    for (int r = ty; r < 32; r += 8)
        tile[r][tx] = in[(size_t)(by + r) * n + bx + tx];
    __syncthreads();
    #pragma unroll
    for (int r = ty; r < 32; r += 8)
        out[(size_t)(bx + r) * n + by + tx] = tile[tx][r];
}

// ---------------------------------------------------------------------------
// 32x32 tiled transpose fp32 -> hi/lo bf16
// ---------------------------------------------------------------------------
__global__ void transpose_split(const float* __restrict__ in, u16* __restrict__ hi,
                                u16* __restrict__ lo, int n) {
    __shared__ float tile[32][33];
    const int bx = blockIdx.x * 32, by = blockIdx.y * 32;
    const int tx = threadIdx.x & 31, ty = threadIdx.x >> 5;
    #pragma unroll
    for (int r = ty; r < 32; r += 8)
        tile[r][tx] = in[(size_t)(by + r) * n + bx + tx];
    __syncthreads();
    #pragma unroll
    for (int r = ty; r < 32; r += 8) {
        float v = tile[tx][r];
        u16 h = f2bf(v);
        size_t o = (size_t)(bx + r) * n + by + tx;
        hi[o] = h;
        lo[o] = f2bf(v - bf2f(h));
    }
}

// ---------------------------------------------------------------------------
// bp[n] = bc[n] + sum_j bv[j] * Wc[j][n]   (bp zeroed first)
// ---------------------------------------------------------------------------
__global__ void bias_kernel(const float* __restrict__ bv, const float* __restrict__ Wc,
                            const float* __restrict__ bc, float* __restrict__ bp) {
    const int n = blockIdx.x * 256 + threadIdx.x;
    const int j0 = blockIdx.y * 128;
    float s = (blockIdx.y == 0) ? bc[n] : 0.0f;
    for (int j = 0; j < 128; ++j)
        s += bv[j0 + j] * Wc[(size_t)(j0 + j) * ED + n];
    atomicAdd(&bp[n], s);
}

// ---------------------------------------------------------------------------
// Split-precision bf16 MFMA GEMM: 128x128 tile, BK=32, 4 waves (2x2).
//   C[M][N] = A[M][K] * B[K][N],  B given transposed [N][K].
//   3-term: Ah*Bh + Ah*Bl + Al*Bh  (~2^-17 rel err).
// LDS layout (slot-major, conflict-free): panel 128x32 bf16 stored as 4 K-slots,
//   element (r, k) at  (k>>3)*1024 + r*8 + (k&7).
//   global_load_lds writes linearly (lane -> consecutive 16B); the per-lane
//   GLOBAL source is permuted to match: call idx in [0,8): slot s=idx&3,
//   half h=idx>>2; lane l sources row h*64+l, cols 8s..8s+7. (rule-21 safe)
//   APRE/BPRE=1: operand pre-split bf16 hi/lo, staged via global_load_lds.
//   APRE/BPRE=0: operand fp32, reg-staged + converted in-kernel (same layout).
//   EPIL=0: Cout[m][n] = acc + bias[n]; EPIL=1: bf16 hi/lo split to Ohi/Olo.
// ---------------------------------------------------------------------------
template<int EPIL, int APRE, int BPRE>
__global__ __launch_bounds__(256)
void gemm3(const float* __restrict__ Af, const u16* __restrict__ Ahi, const u16* __restrict__ Alo,
           const float* __restrict__ Btf, const u16* __restrict__ Bhi, const u16* __restrict__ Blo,
           float* __restrict__ Cout, const float* __restrict__ bias,
           u16* __restrict__ Ohi, u16* __restrict__ Olo, int Kd, int Nd)
{
    __shared__ __align__(16) u16 sAhi[4096];
    __shared__ __align__(16) u16 sAlo[4096];
    __shared__ __align__(16) u16 sBhi[4096];
    __shared__ __align__(16) u16 sBlo[4096];

    const int tid = threadIdx.x, lane = tid & 63, wave = tid >> 6;
    const int wm = wave >> 1, wn = wave & 1;
    const int lrow = lane & 15, kq = lane >> 4;

    // XCD-chunked bijective block swizzle (nwg % 8 == 0 for all launches here)
    const int nwg = gridDim.x * gridDim.y;
    const int lin = blockIdx.y * gridDim.x + blockIdx.x;
    const int lin2 = (lin & 7) * (nwg >> 3) + (lin >> 3);
    const int bx = lin2 % gridDim.x, by = lin2 / gridDim.x;
    const long m0 = (long)bx * 128;
    const long n0 = (long)by * 128;

    // global_load_lds staging geometry (slot-major)
    const int idx0 = wave * 2, idx1 = wave * 2 + 1;
    const int s0 = idx0 & 3, h0 = idx0 >> 2;
    const int s1 = idx1 & 3, h1 = idx1 >> 2;
    const int cb0 = s0 * 1024 + h0 * 512;          // LDS element base (wave-uniform)
    const int cb1 = s1 * 1024 + h1 * 512;
    const long ga0 = (m0 + h0 * 64 + lane) * (long)Kd + s0 * 8;
    const long ga1 = (m0 + h1 * 64 + lane) * (long)Kd + s1 * 8;
    const long gb0 = (n0 + h0 * 64 + lane) * (long)Kd + s0 * 8;
    const long gb1 = (n0 + h1 * 64 + lane) * (long)Kd + s1 * 8;

    f32x4 acc[4][4];
    #pragma unroll
    for (int i = 0; i < 4; ++i)
        #pragma unroll
        for (int j = 0; j < 4; ++j)
            acc[i][j] = (f32x4){0.f, 0.f, 0.f, 0.f};

    float4 av[4], bvv[4];
    if (!APRE) {
        #pragma unroll
        for (int i = 0; i < 4; ++i) {
            int ch = tid + i * 256, r = ch >> 3, c4 = ch & 7;
            av[i] = *reinterpret_cast<const float4*>(Af + (m0 + r) * (long)Kd + c4 * 4);
        }
    }
    if (!BPRE) {
        #pragma unroll
        for (int i = 0; i < 4; ++i) {
            int ch = tid + i * 256, r = ch >> 3, c4 = ch & 7;
            bvv[i] = *reinterpret_cast<const float4*>(Btf + (n0 + r) * (long)Kd + c4 * 4);
        }
    }

    for (int kt = 0; kt < Kd; kt += 32) {
        // ---- stage A ----
        if (APRE) {
            LDSLOAD(Ahi + ga0 + kt, sAhi + cb0);
            LDSLOAD(Ahi + ga1 + kt, sAhi + cb1);
            LDSLOAD(Alo + ga0 + kt, sAlo + cb0);
            LDSLOAD(Alo + ga1 + kt, sAlo + cb1);
        } else {
            #pragma unroll
            for (int i = 0; i < 4; ++i) {
                int ch = tid + i * 256, r = ch >> 3, c4 = ch & 7;
                int off = (c4 >> 1) * 1024 + r * 8 + (c4 & 1) * 4;  // slot-major
                ushort4 h, l;
                h.x = f2bf(av[i].x); l.x = f2bf(av[i].x - bf2f(h.x));
                h.y = f2bf(av[i].y); l.y = f2bf(av[i].y - bf2f(h.y));
                h.z = f2bf(av[i].z); l.z = f2bf(av[i].z - bf2f(h.z));
                h.w = f2bf(av[i].w); l.w = f2bf(av[i].w - bf2f(h.w));
                *reinterpret_cast<ushort4*>(&sAhi[off]) = h;
                *reinterpret_cast<ushort4*>(&sAlo[off]) = l;
            }
        }
        // ---- stage B ----
        if (BPRE) {
            LDSLOAD(Bhi + gb0 + kt, sBhi + cb0);
            LDSLOAD(Bhi + gb1 + kt, sBhi + cb1);
            LDSLOAD(Blo + gb0 + kt, sBlo + cb0);
            LDSLOAD(Blo + gb1 + kt, sBlo + cb1);
        } else {
            #pragma unroll
            for (int i = 0; i < 4; ++i) {
                int ch = tid + i * 256, r = ch >> 3, c4 = ch & 7;
                int off = (c4 >> 1) * 1024 + r * 8 + (c4 & 1) * 4;
                ushort4 h, l;
                h.x = f2bf(bvv[i].x); l.x = f2bf(bvv[i].x - bf2f(h.x));
                h.y = f2bf(bvv[i].y); l.y = f2bf(bvv[i].y - bf2f(h.y));
                h.z = f2bf(bvv[i].z); l.z = f2bf(bvv[i].z - bf2f(h.z));
                h.w = f2bf(bvv[i].w); l.w = f2bf(bvv[i].w - bf2f(h.w));
                *reinterpret_cast<ushort4*>(&sBhi[off]) = h;
                *reinterpret_cast<ushort4*>(&sBlo[off]) = l;
            }
        }

        __syncthreads();   // staging complete (drains vmcnt + lgkm)

        // prefetch next fp32 tiles into regs (overlaps MFMA below)
        if (!APRE && kt + 32 < Kd) {
            #pragma unroll
            for (int i = 0; i < 4; ++i) {
                int ch = tid + i * 256, r = ch >> 3, c4 = ch & 7;
                av[i] = *reinterpret_cast<const float4*>(Af + (m0 + r) * (long)Kd + kt + 32 + c4 * 4);
            }
        }
        if (!BPRE && kt + 32 < Kd) {
            #pragma unroll
            for (int i = 0; i < 4; ++i) {
                int ch = tid + i * 256, r = ch >> 3, c4 = ch & 7;
                bvv[i] = *reinterpret_cast<const float4*>(Btf + (n0 + r) * (long)Kd + kt + 32 + c4 * 4);
            }
        }

        // ---- fragments + 3-term MFMA (slot-major reads: quarter-wave contiguous) ----
        bf16x8 bh[4], bl[4];
        #pragma unroll
        for (int fn = 0; fn < 4; ++fn) {
            int r = wn * 64 + fn * 16 + lrow;
            bh[fn] = *reinterpret_cast<const bf16x8*>(&sBhi[kq * 1024 + r * 8]);
            bl[fn] = *reinterpret_cast<const bf16x8*>(&sBlo[kq * 1024 + r * 8]);
        }
        #pragma unroll
        for (int fm = 0; fm < 4; ++fm) {
            int r = wm * 64 + fm * 16 + lrow;
            bf16x8 ah = *reinterpret_cast<const bf16x8*>(&sAhi[kq * 1024 + r * 8]);
            bf16x8 al = *reinterpret_cast<const bf16x8*>(&sAlo[kq * 1024 + r * 8]);
            #pragma unroll
            for (int fn = 0; fn < 4; ++fn) {
                acc[fm][fn] = __builtin_amdgcn_mfma_f32_16x16x32_bf16(ah, bh[fn], acc[fm][fn], 0, 0, 0);
                acc[fm][fn] = __builtin_amdgcn_mfma_f32_16x16x32_bf16(ah, bl[fn], acc[fm][fn], 0, 0, 0);
                acc[fm][fn] = __builtin_amdgcn_mfma_f32_16x16x32_bf16(al, bh[fn], acc[fm][fn], 0, 0, 0);
            }
        }

        __syncthreads();   // compute done, LDS free for next stage
    }

    // ---- epilogue: C/D layout col=lane&15, row=(lane>>4)*4+i (m89-verified) ----
    #pragma unroll
    for (int fm = 0; fm < 4; ++fm) {
        long gmb = m0 + wm * 64 + fm * 16 + kq * 4;
        #pragma unroll
        for (int fn = 0; fn < 4; ++fn) {
            long gn = n0 + wn * 64 + fn * 16 + lrow;
            float bb = (EPIL == 0) ? bias[gn] : 0.0f;
            #pragma unroll
            for (int i = 0; i < 4; ++i) {
                float w = acc[fm][fn][i];
                if (EPIL == 0) {
                    Cout[(gmb + i) * Nd + gn] = w + bb;
                } else {
                    u16 h = f2bf(w);
                    Ohi[(gmb + i) * Nd + gn] = h;
                    Olo[(gmb + i) * Nd + gn] = f2bf(w - bf2f(h));
                }
            }
        }
    }
}

// ---------------------------------------------------------------------------
// out = x @ (Wv @ Wc) + (bv @ Wc + bc)
//   (attention collapses: einsum sums att over j, softmax rows sum to 1 -> y == v)
// ---------------------------------------------------------------------------
extern "C" void kernel_launch(void* const* d_in, const int* in_sizes, int n_in,
                              void* d_out, int out_size, void* d_ws, size_t ws_size,
                              hipStream_t stream) {
    const float* x  = (const float*)d_in[0];
    const float* Wv = (const float*)d_in[5];
    const float* bv = (const float*)d_in[6];
    const float* Wc = (const float*)d_in[7];
    const float* bc = (const float*)d_in[8];
    float* out = (float*)d_out;

    char* ws = (char*)d_ws;
    const size_t MB = 1024 * 1024;

    // bp always at ws[0] (8KB reserved)
    float* bp = (float*)ws;
    hipMemsetAsync(bp, 0, ED * sizeof(float), stream);
    bias_kernel<<<dim3(ED / 256, ED / 128), 256, 0, stream>>>(bv, Wc, bc, bp);

    if (ws_size >= 80 * MB + 8192) {
        // FULL: pre-split everything; both GEMMs use global_load_lds on all panels
        u16* Wpt_hi = (u16*)(ws + 8192);
        u16* Wpt_lo = (u16*)(ws + 8192 + 8 * MB);
        char* R = ws + 8192 + 16 * MB;          // 64MB region, two lifetimes
        u16* Wct_hi = (u16*)R;                  // phase 1 (32MB)
        u16* Wct_lo = (u16*)(R + 8 * MB);
        u16* Wv_hi  = (u16*)(R + 16 * MB);
        u16* Wv_lo  = (u16*)(R + 24 * MB);
        u16* x_hi   = (u16*)R;                  // phase 2 (64MB, overwrites phase 1)
        u16* x_lo   = (u16*)(R + 32 * MB);

        transpose_split<<<dim3(64, 64), 256, 0, stream>>>(Wc, Wct_hi, Wct_lo, ED);
        split_kernel<<<2048, 256, 0, stream>>>(Wv, Wv_hi, Wv_lo, ED * ED / 4);
        // W'^T = Wc^T @ Wv^T : A=Wct [n][j], B^T=Wv [k][j] -> Wpt [n][k] hi/lo
        gemm3<1, 1, 1><<<dim3(16, 16), 256, 0, stream>>>(
            nullptr, Wct_hi, Wct_lo, nullptr, Wv_hi, Wv_lo,
            nullptr, nullptr, Wpt_hi, Wpt_lo, ED, ED);
        split_kernel<<<2048, 256, 0, stream>>>(x, x_hi, x_lo, MR * ED / 4);
        // out = x @ W' + bp
        gemm3<0, 1, 1><<<dim3(64, 16), 256, 0, stream>>>(
            nullptr, x_hi, x_lo, nullptr, Wpt_hi, Wpt_lo,
            out, bp, nullptr, nullptr, ED, ED);
    } else if (ws_size >= 48 * MB + 8192) {
        // MID: B panels pre-split; A (=x) converted in-kernel
        u16* Wpt_hi = (u16*)(ws + 8192);
        u16* Wpt_lo = (u16*)(ws + 8192 + 8 * MB);
        char* R = ws + 8192 + 16 * MB;
        u16* Wct_hi = (u16*)R;
        u16* Wct_lo = (u16*)(R + 8 * MB);
        u16* Wv_hi  = (u16*)(R + 16 * MB);
        u16* Wv_lo  = (u16*)(R + 24 * MB);

        transpose_split<<<dim3(64, 64), 256, 0, stream>>>(Wc, Wct_hi, Wct_lo, ED);
        split_kernel<<<2048, 256, 0, stream>>>(Wv, Wv_hi, Wv_lo, ED * ED / 4);
        gemm3<1, 1, 1><<<dim3(16, 16), 256, 0, stream>>>(
            nullptr, Wct_hi, Wct_lo, nullptr, Wv_hi, Wv_lo,
            nullptr, nullptr, Wpt_hi, Wpt_lo, ED, ED);
        gemm3<0, 0, 1><<<dim3(64, 16), 256, 0, stream>>>(
            x, nullptr, nullptr, nullptr, Wpt_hi, Wpt_lo,
            out, bp, nullptr, nullptr, ED, ED);
    } else {
        // MINIMAL (~32MB): fp32 operands converted in-kernel for W' GEMM
        float* Wct  = (float*)(ws + 8192);
        u16* Wpt_hi = (u16*)(ws + 8192 + 16 * MB);
        u16* Wpt_lo = (u16*)(ws + 8192 + 24 * MB);

        transpose_f32<<<dim3(64, 64), 256, 0, stream>>>(Wc, Wct, ED);
        gemm3<1, 0, 0><<<dim3(16, 16), 256, 0, stream>>>(
            Wct, nullptr, nullptr, Wv, nullptr, nullptr,
            nullptr, nullptr, Wpt_hi, Wpt_lo, ED, ED);
        gemm3<0, 0, 1><<<dim3(64, 16), 256, 0, stream>>>(
            x, nullptr, nullptr, nullptr, Wpt_hi, Wpt_lo,
            out, bp, nullptr, nullptr, ED, ED);
    }
}

// Round 4
// 532.765 us; speedup vs baseline: 1.1962x; 1.1638x over previous
//
#include <hip/hip_runtime.h>

#define ED 2048
#define MR 8192

typedef unsigned short u16;
typedef __attribute__((ext_vector_type(8))) __bf16 bf16x8;
typedef __attribute__((ext_vector_type(4))) float f32x4;

__device__ __forceinline__ u16 f2bf(float f){ __bf16 h=(__bf16)f; return __builtin_bit_cast(u16,h); }
__device__ __forceinline__ float bf2f(u16 u){ __bf16 h=__builtin_bit_cast(__bf16,u); return (float)h; }

// async global->LDS, 16B per lane; LDS dest is wave-uniform base + lane*16
#define LDSLOAD(gp, lp) __builtin_amdgcn_global_load_lds( \
    (const __attribute__((address_space(1))) unsigned int*)(gp), \
    (__attribute__((address_space(3))) unsigned int*)(lp), 16, 0, 0)

// ---------------------------------------------------------------------------
// split fp32 -> hi/lo bf16 (elementwise, float4 vectorized, grid-stride)
// ---------------------------------------------------------------------------
__global__ void split_kernel(const float* __restrict__ in, u16* __restrict__ hi,
                             u16* __restrict__ lo, int n4) {
    int i = blockIdx.x * 256 + threadIdx.x;
    const int stride = gridDim.x * 256;
    for (; i < n4; i += stride) {
        float4 v = reinterpret_cast<const float4*>(in)[i];
        ushort4 h, l;
        h.x = f2bf(v.x); l.x = f2bf(v.x - bf2f(h.x));
        h.y = f2bf(v.y); l.y = f2bf(v.y - bf2f(h.y));
        h.z = f2bf(v.z); l.z = f2bf(v.z - bf2f(h.z));
        h.w = f2bf(v.w); l.w = f2bf(v.w - bf2f(h.w));
        reinterpret_cast<ushort4*>(hi)[i] = h;
        reinterpret_cast<ushort4*>(lo)[i] = l;
    }
}

// ---------------------------------------------------------------------------
// hi/lo = split(a + b)  — split-K slab reduction, float4 vectorized
// ---------------------------------------------------------------------------
__global__ void reduce2_split(const float* __restrict__ a, const float* __restrict__ b,
                              u16* __restrict__ hi, u16* __restrict__ lo, int n4) {
    int i = blockIdx.x * 256 + threadIdx.x;
    const int stride = gridDim.x * 256;
    for (; i < n4; i += stride) {
        float4 va = reinterpret_cast<const float4*>(a)[i];
        float4 vb = reinterpret_cast<const float4*>(b)[i];
        float4 v; v.x = va.x + vb.x; v.y = va.y + vb.y; v.z = va.z + vb.z; v.w = va.w + vb.w;
        ushort4 h, l;
        h.x = f2bf(v.x); l.x = f2bf(v.x - bf2f(h.x));
        h.y = f2bf(v.y); l.y = f2bf(v.y - bf2f(h.y));
        h.z = f2bf(v.z); l.z = f2bf(v.z - bf2f(h.z));
        h.w = f2bf(v.w); l.w = f2bf(v.w - bf2f(h.w));
        reinterpret_cast<ushort4*>(hi)[i] = h;
        reinterpret_cast<ushort4*>(lo)[i] = l;
    }
}

// ---------------------------------------------------------------------------
// 32x32 tiled transpose fp32 -> fp32 (minimal path)
// ---------------------------------------------------------------------------
__global__ void transpose_f32(const float* __restrict__ in, float* __restrict__ out, int n) {
    __shared__ float tile[32][33];
    const int bx = blockIdx.x * 32, by = blockIdx.y * 32;
    const int tx = threadIdx.x & 31, ty = threadIdx.x >> 5;
    #pragma unroll
    for (int r = ty; r < 32; r += 8)
        tile[r][tx] = in[(size_t)(by + r) * n + bx + tx];
    __syncthreads();
    #pragma unroll
    for (int r = ty; r < 32; r += 8)
        out[(size_t)(bx + r) * n + by + tx] = tile[tx][r];
}

// ---------------------------------------------------------------------------
// 32x32 tiled transpose fp32 -> hi/lo bf16
// ---------------------------------------------------------------------------
__global__ void transpose_split(const float* __restrict__ in, u16* __restrict__ hi,
                                u16* __restrict__ lo, int n) {
    __shared__ float tile[32][33];
    const int bx = blockIdx.x * 32, by = blockIdx.y * 32;
    const int tx = threadIdx.x & 31, ty = threadIdx.x >> 5;
    #pragma unroll
    for (int r = ty; r < 32; r += 8)
        tile[r][tx] = in[(size_t)(by + r) * n + bx + tx];
    __syncthreads();
    #pragma unroll
    for (int r = ty; r < 32; r += 8) {
        float v = tile[tx][r];
        u16 h = f2bf(v);
        size_t o = (size_t)(bx + r) * n + by + tx;
        hi[o] = h;
        lo[o] = f2bf(v - bf2f(h));
    }
}

// ---------------------------------------------------------------------------
// bp[n] += (bc[n] if first chunk) + sum_{j in chunk of 64} bv[j]*Wc[j][n]
// grid (ED/256, ED/64) = (8, 32), 256 threads; bp zeroed first.
// ---------------------------------------------------------------------------
__global__ void bias_kernel(const float* __restrict__ bv, const float* __restrict__ Wc,
                            const float* __restrict__ bc, float* __restrict__ bp) {
    const int n = blockIdx.x * 256 + threadIdx.x;
    const int j0 = blockIdx.y * 64;
    float s = (blockIdx.y == 0) ? bc[n] : 0.0f;
    #pragma unroll 4
    for (int j = 0; j < 64; ++j)
        s += bv[j0 + j] * Wc[(size_t)(j0 + j) * ED + n];
    atomicAdd(&bp[n], s);
}

// ===========================================================================
// MAIN GEMM: 256x256 tile, BK=32, 8 waves (2x4), double-buffered LDS (128KB),
// counted-vmcnt 2-phase pipeline (T3-minimum recipe).
//   C[M][N] = A[M][K] * B[K][N] + bias;  A,B pre-split bf16 hi/lo, B as [N][K].
//   3-term: Ah*Bh + Ah*Bl + Al*Bh.
// LDS slot-major per panel (256x32 bf16): elem (r,k) at (k>>3)*2048 + r*8 + (k&7)
//   -> global_load_lds chunk q=c*64+lane maps row (c&3)*64+lane, k-slot c>>2;
//      fragment ds_read_b128 quarter-wave contiguous (conflict-free).
// Pipeline per K-step t: stage(t+1 -> buf^1) [8 glds/wave]; vmcnt(8) [waits
//   stage(t) only]; s_barrier; 24 ds_read + 96 MFMA on buf; s_barrier.
// ===========================================================================
__global__ __launch_bounds__(512, 2)
void gemm256(const u16* __restrict__ Ahi, const u16* __restrict__ Alo,
             const u16* __restrict__ Bhi, const u16* __restrict__ Blo,
             float* __restrict__ Cout, const float* __restrict__ bias,
             int Kd, int Nd)
{
    __shared__ __align__(16) u16 sAhi[2][8192];
    __shared__ __align__(16) u16 sAlo[2][8192];
    __shared__ __align__(16) u16 sBhi[2][8192];
    __shared__ __align__(16) u16 sBlo[2][8192];

    const int tid = threadIdx.x, lane = tid & 63, wave = tid >> 6;
    const int wm = wave >> 2, wn = wave & 3;          // 2 x 4 wave grid
    const int lrow = lane & 15, kq = lane >> 4;

    // XCD-chunked bijective swizzle (nwg = 256, %8 == 0)
    const int nwg = gridDim.x * gridDim.y;
    const int lin = blockIdx.y * gridDim.x + blockIdx.x;
    const int lin2 = (lin & 7) * (nwg >> 3) + (lin >> 3);
    const int bx = lin2 % gridDim.x, by = lin2 / gridDim.x;
    const long m0 = (long)bx * 256;
    const long n0 = (long)by * 256;

    // staging: 16 chunks-of-call c per plane; wave handles c0=wave*2, c1=c0+1.
    // call c: k-slot s=c>>2, rows (c&3)*64 + lane, LDS elem base c*512.
    const int c0 = wave * 2, c1 = c0 + 1;
    const int lb0 = c0 * 512, lb1 = c1 * 512;
    const long ga0 = (m0 + (c0 & 3) * 64 + lane) * (long)Kd + (c0 >> 2) * 8;
    const long ga1 = (m0 + (c1 & 3) * 64 + lane) * (long)Kd + (c1 >> 2) * 8;
    const long gb0 = (n0 + (c0 & 3) * 64 + lane) * (long)Kd + (c0 >> 2) * 8;
    const long gb1 = (n0 + (c1 & 3) * 64 + lane) * (long)Kd + (c1 >> 2) * 8;

    f32x4 acc[8][4];
    #pragma unroll
    for (int i = 0; i < 8; ++i)
        #pragma unroll
        for (int j = 0; j < 4; ++j)
            acc[i][j] = (f32x4){0.f, 0.f, 0.f, 0.f};

#define STAGE(buf, kt) do { \
    LDSLOAD(Ahi + ga0 + (kt), &sAhi[buf][lb0]); \
    LDSLOAD(Ahi + ga1 + (kt), &sAhi[buf][lb1]); \
    LDSLOAD(Alo + ga0 + (kt), &sAlo[buf][lb0]); \
    LDSLOAD(Alo + ga1 + (kt), &sAlo[buf][lb1]); \
    LDSLOAD(Bhi + gb0 + (kt), &sBhi[buf][lb0]); \
    LDSLOAD(Bhi + gb1 + (kt), &sBhi[buf][lb1]); \
    LDSLOAD(Blo + gb0 + (kt), &sBlo[buf][lb0]); \
    LDSLOAD(Blo + gb1 + (kt), &sBlo[buf][lb1]); \
} while (0)

    const int NT = Kd >> 5;   // 64
    STAGE(0, 0);

    for (int t = 0; t < NT; ++t) {
        const int cur = t & 1;
        if (t + 1 < NT) {
            STAGE(cur ^ 1, (t + 1) << 5);
            asm volatile("s_waitcnt vmcnt(8)" ::: "memory");   // stage(t) done, stage(t+1) in flight
        } else {
            asm volatile("s_waitcnt vmcnt(0)" ::: "memory");
        }
        __builtin_amdgcn_s_barrier();       // buf[cur] ready on all waves
        __builtin_amdgcn_sched_barrier(0);

        // ---- 24 ds_read_b128 + 96 MFMA ----
        bf16x8 bh[4], bl[4];
        #pragma unroll
        for (int fn = 0; fn < 4; ++fn) {
            int off = kq * 2048 + (wn * 64 + fn * 16 + lrow) * 8;
            bh[fn] = *reinterpret_cast<const bf16x8*>(&sBhi[cur][off]);
            bl[fn] = *reinterpret_cast<const bf16x8*>(&sBlo[cur][off]);
        }
        #pragma unroll
        for (int fm = 0; fm < 8; ++fm) {
            int off = kq * 2048 + (wm * 128 + fm * 16 + lrow) * 8;
            bf16x8 ah = *reinterpret_cast<const bf16x8*>(&sAhi[cur][off]);
            bf16x8 al = *reinterpret_cast<const bf16x8*>(&sAlo[cur][off]);
            #pragma unroll
            for (int fn = 0; fn < 4; ++fn) {
                acc[fm][fn] = __builtin_amdgcn_mfma_f32_16x16x32_bf16(ah, bh[fn], acc[fm][fn], 0, 0, 0);
                acc[fm][fn] = __builtin_amdgcn_mfma_f32_16x16x32_bf16(ah, bl[fn], acc[fm][fn], 0, 0, 0);
                acc[fm][fn] = __builtin_amdgcn_mfma_f32_16x16x32_bf16(al, bh[fn], acc[fm][fn], 0, 0, 0);
            }
        }

        __builtin_amdgcn_sched_barrier(0);
        __builtin_amdgcn_s_barrier();       // all waves done reading buf[cur]
    }
#undef STAGE

    // epilogue: C/D layout col=lane&15, row=(lane>>4)*4+i (m89-verified)
    #pragma unroll
    for (int fm = 0; fm < 8; ++fm) {
        long gmb = m0 + wm * 128 + fm * 16 + kq * 4;
        #pragma unroll
        for (int fn = 0; fn < 4; ++fn) {
            long gn = n0 + wn * 64 + fn * 16 + lrow;
            float bb = bias[gn];
            #pragma unroll
            for (int i = 0; i < 4; ++i)
                Cout[(gmb + i) * Nd + gn] = acc[fm][fn][i] + bb;
        }
    }
}

// ---------------------------------------------------------------------------
// 128x128 GEMM (round-3 structure) for the weight-product + fallback paths.
//   EPIL=0: fp32 +bias; EPIL=1: bf16 hi/lo split; EPIL=2: fp32 slab write,
//   slab chosen by blockIdx.z (split-K: koff = z*Kd, slab offset z*M*Nd).
//   Ld = leading dim of A/B rows (full K), Kd = K-chunk length iterated.
// ---------------------------------------------------------------------------
template<int EPIL, int APRE, int BPRE>
__global__ __launch_bounds__(256)
void gemm3(const float* __restrict__ Af, const u16* __restrict__ Ahi, const u16* __restrict__ Alo,
           const float* __restrict__ Btf, const u16* __restrict__ Bhi, const u16* __restrict__ Blo,
           float* __restrict__ Cout, const float* __restrict__ bias,
           u16* __restrict__ Ohi, u16* __restrict__ Olo, int Kd, int Ld, int Nd)
{
    __shared__ __align__(16) u16 sAhi[4096];
    __shared__ __align__(16) u16 sAlo[4096];
    __shared__ __align__(16) u16 sBhi[4096];
    __shared__ __align__(16) u16 sBlo[4096];

    const int tid = threadIdx.x, lane = tid & 63, wave = tid >> 6;
    const int wm = wave >> 1, wn = wave & 1;
    const int lrow = lane & 15, kq = lane >> 4;

    const int nwg = gridDim.x * gridDim.y;
    const int lin = blockIdx.y * gridDim.x + blockIdx.x;
    const int lin2 = (lin & 7) * (nwg >> 3) + (lin >> 3);
    const int bx = lin2 % gridDim.x, by = lin2 / gridDim.x;
    const long m0 = (long)bx * 128;
    const long n0 = (long)by * 128;
    const long koff = (long)blockIdx.z * Kd;
    if (EPIL == 2) Cout += (size_t)blockIdx.z * (size_t)gridDim.x * 128 * Nd;

    const int idx0 = wave * 2, idx1 = wave * 2 + 1;
    const int s0 = idx0 & 3, h0 = idx0 >> 2;
    const int s1 = idx1 & 3, h1 = idx1 >> 2;
    const int cb0 = s0 * 1024 + h0 * 512;
    const int cb1 = s1 * 1024 + h1 * 512;
    const long ga0 = (m0 + h0 * 64 + lane) * (long)Ld + koff + s0 * 8;
    const long ga1 = (m0 + h1 * 64 + lane) * (long)Ld + koff + s1 * 8;
    const long gb0 = (n0 + h0 * 64 + lane) * (long)Ld + koff + s0 * 8;
    const long gb1 = (n0 + h1 * 64 + lane) * (long)Ld + koff + s1 * 8;

    f32x4 acc[4][4];
    #pragma unroll
    for (int i = 0; i < 4; ++i)
        #pragma unroll
        for (int j = 0; j < 4; ++j)
            acc[i][j] = (f32x4){0.f, 0.f, 0.f, 0.f};

    float4 av[4], bvv[4];
    if (!APRE) {
        #pragma unroll
        for (int i = 0; i < 4; ++i) {
            int ch = tid + i * 256, r = ch >> 3, c4 = ch & 7;
            av[i] = *reinterpret_cast<const float4*>(Af + (m0 + r) * (long)Ld + koff + c4 * 4);
        }
    }
    if (!BPRE) {
        #pragma unroll
        for (int i = 0; i < 4; ++i) {
            int ch = tid + i * 256, r = ch >> 3, c4 = ch & 7;
            bvv[i] = *reinterpret_cast<const float4*>(Btf + (n0 + r) * (long)Ld + koff + c4 * 4);
        }
    }

    for (int kt = 0; kt < Kd; kt += 32) {
        if (APRE) {
            LDSLOAD(Ahi + ga0 + kt, sAhi + cb0);
            LDSLOAD(Ahi + ga1 + kt, sAhi + cb1);
            LDSLOAD(Alo + ga0 + kt, sAlo + cb0);
            LDSLOAD(Alo + ga1 + kt, sAlo + cb1);
        } else {
            #pragma unroll
            for (int i = 0; i < 4; ++i) {
                int ch = tid + i * 256, r = ch >> 3, c4 = ch & 7;
                int off = (c4 >> 1) * 1024 + r * 8 + (c4 & 1) * 4;
                ushort4 h, l;
                h.x = f2bf(av[i].x); l.x = f2bf(av[i].x - bf2f(h.x));
                h.y = f2bf(av[i].y); l.y = f2bf(av[i].y - bf2f(h.y));
                h.z = f2bf(av[i].z); l.z = f2bf(av[i].z - bf2f(h.z));
                h.w = f2bf(av[i].w); l.w = f2bf(av[i].w - bf2f(h.w));
                *reinterpret_cast<ushort4*>(&sAhi[off]) = h;
                *reinterpret_cast<ushort4*>(&sAlo[off]) = l;
            }
        }
        if (BPRE) {
            LDSLOAD(Bhi + gb0 + kt, sBhi + cb0);
            LDSLOAD(Bhi + gb1 + kt, sBhi + cb1);
            LDSLOAD(Blo + gb0 + kt, sBlo + cb0);
            LDSLOAD(Blo + gb1 + kt, sBlo + cb1);
        } else {
            #pragma unroll
            for (int i = 0; i < 4; ++i) {
                int ch = tid + i * 256, r = ch >> 3, c4 = ch & 7;
                int off = (c4 >> 1) * 1024 + r * 8 + (c4 & 1) * 4;
                ushort4 h, l;
                h.x = f2bf(bvv[i].x); l.x = f2bf(bvv[i].x - bf2f(h.x));
                h.y = f2bf(bvv[i].y); l.y = f2bf(bvv[i].y - bf2f(h.y));
                h.z = f2bf(bvv[i].z); l.z = f2bf(bvv[i].z - bf2f(h.z));
                h.w = f2bf(bvv[i].w); l.w = f2bf(bvv[i].w - bf2f(h.w));
                *reinterpret_cast<ushort4*>(&sBhi[off]) = h;
                *reinterpret_cast<ushort4*>(&sBlo[off]) = l;
            }
        }

        __syncthreads();

        if (!APRE && kt + 32 < Kd) {
            #pragma unroll
            for (int i = 0; i < 4; ++i) {
                int ch = tid + i * 256, r = ch >> 3, c4 = ch & 7;
                av[i] = *reinterpret_cast<const float4*>(Af + (m0 + r) * (long)Ld + koff + kt + 32 + c4 * 4);
            }
        }
        if (!BPRE && kt + 32 < Kd) {
            #pragma unroll
            for (int i = 0; i < 4; ++i) {
                int ch = tid + i * 256, r = ch >> 3, c4 = ch & 7;
                bvv[i] = *reinterpret_cast<const float4*>(Btf + (n0 + r) * (long)Ld + koff + kt + 32 + c4 * 4);
            }
        }

        bf16x8 bh[4], bl[4];
        #pragma unroll
        for (int fn = 0; fn < 4; ++fn) {
            int r = wn * 64 + fn * 16 + lrow;
            bh[fn] = *reinterpret_cast<const bf16x8*>(&sBhi[kq * 1024 + r * 8]);
            bl[fn] = *reinterpret_cast<const bf16x8*>(&sBlo[kq * 1024 + r * 8]);
        }
        #pragma unroll
        for (int fm = 0; fm < 4; ++fm) {
            int r = wm * 64 + fm * 16 + lrow;
            bf16x8 ah = *reinterpret_cast<const bf16x8*>(&sAhi[kq * 1024 + r * 8]);
            bf16x8 al = *reinterpret_cast<const bf16x8*>(&sAlo[kq * 1024 + r * 8]);
            #pragma unroll
            for (int fn = 0; fn < 4; ++fn) {
                acc[fm][fn] = __builtin_amdgcn_mfma_f32_16x16x32_bf16(ah, bh[fn], acc[fm][fn], 0, 0, 0);
                acc[fm][fn] = __builtin_amdgcn_mfma_f32_16x16x32_bf16(ah, bl[fn], acc[fm][fn], 0, 0, 0);
                acc[fm][fn] = __builtin_amdgcn_mfma_f32_16x16x32_bf16(al, bh[fn], acc[fm][fn], 0, 0, 0);
            }
        }

        __syncthreads();
    }

    #pragma unroll
    for (int fm = 0; fm < 4; ++fm) {
        long gmb = m0 + wm * 64 + fm * 16 + kq * 4;
        #pragma unroll
        for (int fn = 0; fn < 4; ++fn) {
            long gn = n0 + wn * 64 + fn * 16 + lrow;
            float bb = (EPIL == 0) ? bias[gn] : 0.0f;
            #pragma unroll
            for (int i = 0; i < 4; ++i) {
                float w = acc[fm][fn][i];
                if (EPIL == 0) {
                    Cout[(gmb + i) * Nd + gn] = w + bb;
                } else if (EPIL == 2) {
                    Cout[(gmb + i) * Nd + gn] = w;
                } else {
                    u16 h = f2bf(w);
                    Ohi[(gmb + i) * Nd + gn] = h;
                    Olo[(gmb + i) * Nd + gn] = f2bf(w - bf2f(h));
                }
            }
        }
    }
}

// ---------------------------------------------------------------------------
// out = x @ (Wv @ Wc) + (bv @ Wc + bc)
//   (attention collapses: einsum sums att over j; softmax rows sum to 1 -> y == v)
// ---------------------------------------------------------------------------
extern "C" void kernel_launch(void* const* d_in, const int* in_sizes, int n_in,
                              void* d_out, int out_size, void* d_ws, size_t ws_size,
                              hipStream_t stream) {
    const float* x  = (const float*)d_in[0];
    const float* Wv = (const float*)d_in[5];
    const float* bv = (const float*)d_in[6];
    const float* Wc = (const float*)d_in[7];
    const float* bc = (const float*)d_in[8];
    float* out = (float*)d_out;

    char* ws = (char*)d_ws;
    const size_t MB = 1024 * 1024;

    float* bp = (float*)ws;                 // 8KB reserved
    hipMemsetAsync(bp, 0, ED * sizeof(float), stream);
    bias_kernel<<<dim3(ED / 256, ED / 64), 256, 0, stream>>>(bv, Wc, bc, bp);

    if (ws_size >= 80 * MB + 8192) {
        // FULL: pre-split all; W' via split-K=2 slabs; main = gemm256 pipeline
        u16* Wpt_hi = (u16*)(ws + 8192);
        u16* Wpt_lo = (u16*)(ws + 8192 + 8 * MB);
        char* R = ws + 8192 + 16 * MB;          // 64MB region, two lifetimes
        u16* Wct_hi = (u16*)R;                  // phase 1
        u16* Wct_lo = (u16*)(R + 8 * MB);
        u16* Wv_hi  = (u16*)(R + 16 * MB);
        u16* Wv_lo  = (u16*)(R + 24 * MB);
        float* slab = (float*)(R + 32 * MB);    // 2 x 16MB contiguous
        u16* x_hi   = (u16*)R;                  // phase 2 (overwrites phase 1)
        u16* x_lo   = (u16*)(R + 32 * MB);

        transpose_split<<<dim3(64, 64), 256, 0, stream>>>(Wc, Wct_hi, Wct_lo, ED);
        split_kernel<<<2048, 256, 0, stream>>>(Wv, Wv_hi, Wv_lo, ED * ED / 4);
        // W'^T = Wc^T @ Wv^T, split-K=2 into fp32 slabs
        gemm3<2, 1, 1><<<dim3(16, 16, 2), 256, 0, stream>>>(
            nullptr, Wct_hi, Wct_lo, nullptr, Wv_hi, Wv_lo,
            slab, nullptr, nullptr, nullptr, ED / 2, ED, ED);
        reduce2_split<<<2048, 256, 0, stream>>>(slab, slab + (size_t)ED * ED,
                                                Wpt_hi, Wpt_lo, ED * ED / 4);
        split_kernel<<<2048, 256, 0, stream>>>(x, x_hi, x_lo, MR * ED / 4);
        // out = x @ W' + bp  (256^2 double-buffered pipeline)
        gemm256<<<dim3(MR / 256, ED / 256), 512, 0, stream>>>(
            x_hi, x_lo, Wpt_hi, Wpt_lo, out, bp, ED, ED);
    } else if (ws_size >= 48 * MB + 8192) {
        // MID: B panels pre-split; x converted in-kernel (128^2 path)
        u16* Wpt_hi = (u16*)(ws + 8192);
        u16* Wpt_lo = (u16*)(ws + 8192 + 8 * MB);
        char* R = ws + 8192 + 16 * MB;
        u16* Wct_hi = (u16*)R;
        u16* Wct_lo = (u16*)(R + 8 * MB);
        u16* Wv_hi  = (u16*)(R + 16 * MB);
        u16* Wv_lo  = (u16*)(R + 24 * MB);

        transpose_split<<<dim3(64, 64), 256, 0, stream>>>(Wc, Wct_hi, Wct_lo, ED);
        split_kernel<<<2048, 256, 0, stream>>>(Wv, Wv_hi, Wv_lo, ED * ED / 4);
        gemm3<1, 1, 1><<<dim3(16, 16), 256, 0, stream>>>(
            nullptr, Wct_hi, Wct_lo, nullptr, Wv_hi, Wv_lo,
            nullptr, nullptr, Wpt_hi, Wpt_lo, ED, ED, ED);
        gemm3<0, 0, 1><<<dim3(64, 16), 256, 0, stream>>>(
            x, nullptr, nullptr, nullptr, Wpt_hi, Wpt_lo,
            out, bp, nullptr, nullptr, ED, ED, ED);
    } else {
        // MINIMAL (~32MB)
        float* Wct  = (float*)(ws + 8192);
        u16* Wpt_hi = (u16*)(ws + 8192 + 16 * MB);
        u16* Wpt_lo = (u16*)(ws + 8192 + 24 * MB);

        transpose_f32<<<dim3(64, 64), 256, 0, stream>>>(Wc, Wct, ED);
        gemm3<1, 0, 0><<<dim3(16, 16), 256, 0, stream>>>(
            Wct, nullptr, nullptr, Wv, nullptr, nullptr,
            nullptr, nullptr, Wpt_hi, Wpt_lo, ED, ED, ED);
        gemm3<0, 0, 1><<<dim3(64, 16), 256, 0, stream>>>(
            x, nullptr, nullptr, nullptr, Wpt_hi, Wpt_lo,
            out, bp, nullptr, nullptr, ED, ED, ED);
    }
}